// Round 6
// baseline (86.691 us; speedup 1.0000x reference)
//
#include <hip/hip_runtime.h>
#include <math.h>

#define NWIRES 6
#define DIM 64
#define NTOK 32768            // B*T = 16*2048
#define NBATCH 16
#define TPB 2048              // tokens per batch
#define NMOM 16               // Taylor order: exp(az), |az|<=sqrt(6); rem ~8e-8
#define SQRT6F 2.4494897427831781f
#define APAD 76               // LDS row stride (ushorts), conflict-benign (R12)
#define ZPH 132               // zpow/vT row stride for 128 tokens (16B-aligned)

typedef short bf16x8 __attribute__((ext_vector_type(8)));
typedef float f32x4  __attribute__((ext_vector_type(4)));

__device__ __forceinline__ unsigned f2bfbits(float f) {   // RNE fp32->bf16 bits
    unsigned u = __float_as_uint(f);
    return (u + 0x7FFF + ((u >> 16) & 1)) >> 16;
}
__device__ __forceinline__ float bfbits2f(unsigned b) {
    return __uint_as_float(b << 16);
}
__device__ __forceinline__ float pswap(float v) { return __shfl_xor(v, 1, 64); }

// ---------------------------------------------------------------------------
// R19: balanced blocks.  R18 post-mortem: cooperative grid.sync under graph
// capture is broken (race, varying absmax) -> 2 regular dispatches is the
// floor.  R17's asymmetry made KV blocks (2 circuits + moments) the critical
// path at ~2x a Q block.  Now all 256 blocks are IDENTICAL: block bx owns
// tokens [bx*128, bx*128+128) and runs Q, K, AND V circuits on them
// (1.5 circuit-units/block, x loaded+converted ONCE), then computes its
// 128-token moment partial -> mpart[bx].  Per-token MFMA math, APAD
// geometry, epilogue, accumulation order: byte-identical to R12-R17.
// LDS: 6 A-planes (114KB) + moments arrays ~= 122KB -> 1 block/CU.
// ---------------------------------------------------------------------------

// A-build device fn: angle tables + R12 half-column evolution -> sAh/sAl.
// Called by ALL threads of the block (contains barriers).
__device__ __forceinline__ void build_A(const float* __restrict__ p,
        unsigned short* sAh, unsigned short* sAl,
        float* sTc, float* sTs, float* sP, int tid) {
    if (tid < 64) {
        int b = tid;
        float d = 0.f;
#pragma unroll
        for (int j = 0; j < 6; ++j)
            d += 0.5f * p[j] * ((b & (32 >> j)) ? -1.f : 1.f);
        float sd, cd;
        sincosf(d, &sd, &cd);
        sTc[b] = cd;
        sTs[b] = sd;
        if (b < 12) {                     // p[6..11]=RY0, p[12..17]=RY1
            float s, cc;
            sincosf(0.5f * p[6 + b], &s, &cc);
            sP[b * 2 + 0] = cc;
            sP[b * 2 + 1] = s;
        }
    }
    __syncthreads();

    {
        int ph = tid >> 7;                // 0: cos rows, 1: sin rows
        int k  = (tid >> 1) & 63;         // column
        int h  = tid & 1;                 // bit5 (value 32) of row index
        const float* sTx = ph ? sTs : sTc;
        float v[32];
#pragma unroll
        for (int i = 0; i < 32; ++i) {
            int g = h * 32 + i;
            v[i] = (__popc(g & k) & 1) ? -sTx[g] : sTx[g];   // diag(T) W e_k
        }
        // Walsh stage M=32 (split): lo'=lo+hi, hi'=lo-hi
#pragma unroll
        for (int i = 0; i < 32; ++i) {
            float pv_ = pswap(v[i]);
            v[i] = h ? (pv_ - v[i]) : (v[i] + pv_);
        }
        // Walsh stages M=16..1 (local)
#pragma unroll
        for (int M = 16; M >= 1; M >>= 1) {
#pragma unroll
            for (int i = 0; i < 32; ++i) {
                if (i & M) continue;
                int j = i | M;
                float a = v[i], b = v[j];
                v[i] = a + b; v[j] = a - b;
            }
        }
        // RY0 then CNOT ring then RY1
#pragma unroll
        for (int layer = 0; layer < 2; ++layer) {
            const float* Pl = sP + layer * 12;
            {
                float c = Pl[0], ss = h ? Pl[1] : -Pl[1];
#pragma unroll
                for (int i = 0; i < 32; ++i) {
                    float pv_ = pswap(v[i]);
                    v[i] = c * v[i] + ss * pv_;
                }
            }
#pragma unroll
            for (int w = 1; w < 6; ++w) {
                int M = 32 >> w;
                float c = Pl[w * 2], s = Pl[w * 2 + 1];
#pragma unroll
                for (int i = 0; i < 32; ++i) {
                    if (i & M) continue;
                    int j = i | M;
                    float a = v[i], b = v[j];
                    v[i] = c * a - s * b;
                    v[j] = s * a + c * b;
                }
            }
            if (layer == 0) {
                // CNOT(0,1): control bit32 (h), target 16
#pragma unroll
                for (int i = 0; i < 16; ++i) {
                    int j = i | 16;
                    float a = v[i], b = v[j];
                    v[i] = h ? b : a;
                    v[j] = h ? a : b;
                }
                // CNOT(1,2)(2,3)(3,4)(4,5): local renames
#pragma unroll
                for (int w = 1; w < 5; ++w) {
                    int MC = 32 >> w, MT = MC >> 1;
#pragma unroll
                    for (int i = 0; i < 32; ++i) {
                        if (!(i & MC) || (i & MT)) continue;
                        int j = i | MT;
                        float t = v[i]; v[i] = v[j]; v[j] = t;
                    }
                }
                // CNOT(5,0): control bit0, target bit32
#pragma unroll
                for (int i = 1; i < 32; i += 2) v[i] = pswap(v[i]);
            }
        }
        // pack bf16 hi/lo into LDS
#pragma unroll
        for (int i = 0; i < 32; ++i) {
            int row = ph * 64 + h * 32 + i;
            unsigned hb = f2bfbits(v[i]);
            unsigned lb = f2bfbits(v[i] - bfbits2f(hb));
            sAh[row * APAD + k] = (unsigned short)hb;
            sAl[row * APAD + k] = (unsigned short)lb;
        }
    }
    __syncthreads();
}

__global__ __attribute__((amdgpu_waves_per_eu(1, 4)))
__launch_bounds__(256) void qsa_sim(
        const float* __restrict__ x,
        const float* __restrict__ pq,
        const float* __restrict__ pk,
        const float* __restrict__ pv,
        float* __restrict__ zq,
        float* __restrict__ mpart) {
    __shared__ __align__(16) unsigned short sAbuf[6 * 128 * APAD];  // 116736 B
    __shared__ float sTc[64], sTs[64], sP[24];
    __shared__ float zT[128];                       // K-circuit z per token
    __shared__ __align__(16) float vT[6 * ZPH];     // V outputs, transposed
    __shared__ float sred[224];
    int tid = threadIdx.x;
    int bx = blockIdx.x;                            // 0..255
    int tbase = bx * 128;

    // ---- issue all X loads first (wave's 32 tokens; overlap with builds) ----
    int lane = tid & 63, wv = tid >> 6;
    int q4 = lane >> 4, c16 = lane & 15;
    float4 rw[8];
#pragma unroll
    for (int cg = 0; cg < 2; ++cg) {
        const float* xr = x + ((size_t)(tbase + wv * 32 + cg * 16 + c16)) * 64;
#pragma unroll
        for (int ks = 0; ks < 2; ++ks) {
            rw[cg * 4 + ks * 2 + 0] = *(const float4*)(xr + ks * 32 + q4 * 8);
            rw[cg * 4 + ks * 2 + 1] = *(const float4*)(xr + ks * 32 + q4 * 8 + 4);
        }
    }

    // ---- build all three A matrices (Q, K, V) ----
    build_A(pq, sAbuf + 0 * 128 * APAD, sAbuf + 1 * 128 * APAD, sTc, sTs, sP, tid);
    build_A(pk, sAbuf + 2 * 128 * APAD, sAbuf + 3 * 128 * APAD, sTc, sTs, sP, tid);
    build_A(pv, sAbuf + 4 * 128 * APAD, sAbuf + 5 * 128 * APAD, sTc, sTs, sP, tid);

    // ---- convert x -> bf16 hi/lo fragments ONCE (shared by Q/K/V) ----
    bf16x8 xh[2][2], xl[2][2];
#pragma unroll
    for (int cg = 0; cg < 2; ++cg) {
#pragma unroll
        for (int ks = 0; ks < 2; ++ks) {
            float4 f0 = rw[cg * 4 + ks * 2], f1 = rw[cg * 4 + ks * 2 + 1];
            float ff[8] = {f0.x, f0.y, f0.z, f0.w, f1.x, f1.y, f1.z, f1.w};
#pragma unroll
            for (int e = 0; e < 8; ++e) {
                unsigned hb = f2bfbits(ff[e]);
                unsigned lb = f2bfbits(ff[e] - bfbits2f(hb));
                xh[cg][ks][e] = (short)hb;
                xl[cg][ks][e] = (short)lb;
            }
        }
    }

    // ---- MFMA: 3 circuits x 2 chunk-groups on the same x fragments ----
#pragma unroll 1
    for (int cc = 0; cc < 3; ++cc) {
        const unsigned short* Ah = sAbuf + cc * (2 * 128 * APAD);
        const unsigned short* Al = Ah + 128 * APAD;

        f32x4 acc[2][8];
#pragma unroll
        for (int cg = 0; cg < 2; ++cg)
#pragma unroll
            for (int mt = 0; mt < 8; ++mt) acc[cg][mt] = (f32x4){0.f, 0.f, 0.f, 0.f};

#pragma unroll
        for (int mt = 0; mt < 8; ++mt) {
            int r = mt * 16 + c16;               // A-op row m
#pragma unroll
            for (int ks = 0; ks < 2; ++ks) {
                const uint2* ph_ = (const uint2*)(&Ah[r * APAD + ks * 32 + q4 * 8]);
                const uint2* pl_ = (const uint2*)(&Al[r * APAD + ks * 32 + q4 * 8]);
                union { uint2 u[2]; bf16x8 v; } ua, ub;
                ua.u[0] = ph_[0]; ua.u[1] = ph_[1];
                ub.u[0] = pl_[0]; ub.u[1] = pl_[1];
                bf16x8 ah = ua.v, al = ub.v;
#pragma unroll
                for (int cg = 0; cg < 2; ++cg) {
                    acc[cg][mt] = __builtin_amdgcn_mfma_f32_16x16x32_bf16(ah, xh[cg][ks], acc[cg][mt], 0, 0, 0);
                    acc[cg][mt] = __builtin_amdgcn_mfma_f32_16x16x32_bf16(ah, xl[cg][ks], acc[cg][mt], 0, 0, 0);
                    acc[cg][mt] = __builtin_amdgcn_mfma_f32_16x16x32_bf16(al, xh[cg][ks], acc[cg][mt], 0, 0, 0);
                }
            }
        }

        // epilogue per chunk-group (R12-verified math)
#pragma unroll
        for (int cg = 0; cg < 2; ++cg) {
            float n = 0.f, s0 = 0.f, s1 = 0.f, s2 = 0.f, s3 = 0.f, s4 = 0.f, s5 = 0.f;
            float f2 = (q4 < 2) ? 1.f : 0.f;         // r bit3 == 0
            float f3 = (q4 & 1) ? 0.f : 1.f;         // r bit2 == 0
#pragma unroll
            for (int mt = 0; mt < 4; ++mt) {
#pragma unroll
                for (int rg = 0; rg < 4; ++rg) {
                    float dc = acc[cg][mt][rg];      // row r = mt*16 + q4*4 + rg
                    float ds = acc[cg][mt + 4][rg];  // row r + 64
                    float pp = dc * dc + ds * ds;
                    n += pp;
                    if (!(mt & 2)) s0 += pp;         // bit5
                    if (!(mt & 1)) s1 += pp;         // bit4
                    s2 += f2 * pp;                   // bit3
                    s3 += f3 * pp;                   // bit2
                    if (!(rg & 2)) s4 += pp;         // bit1
                    if (!(rg & 1)) s5 += pp;         // bit0
                }
            }
#pragma unroll
            for (int d = 16; d <= 32; d <<= 1) {
                n  += __shfl_xor(n,  d, 64);
                s0 += __shfl_xor(s0, d, 64);
                s1 += __shfl_xor(s1, d, 64);
                s2 += __shfl_xor(s2, d, 64);
                s3 += __shfl_xor(s3, d, 64);
                s4 += __shfl_xor(s4, d, 64);
                s5 += __shfl_xor(s5, d, 64);
            }
            if (q4 == 0) {
                int tl = wv * 32 + cg * 16 + c16;    // 0..127
                float inv = 1.0f / n;
                if (cc == 0) {
                    zq[tbase + tl] = SQRT6F * (2.f * s0 - n) * inv;  // a_t
                } else if (cc == 1) {
                    zT[tl] = (2.f * s0 - n) * inv;                   // K z
                } else {
                    vT[0 * ZPH + tl] = (2.f * s0 - n) * inv;
                    vT[1 * ZPH + tl] = (2.f * s1 - n) * inv;
                    vT[2 * ZPH + tl] = (2.f * s2 - n) * inv;
                    vT[3 * ZPH + tl] = (2.f * s3 - n) * inv;
                    vT[4 * ZPH + tl] = (2.f * s4 - n) * inv;
                    vT[5 * ZPH + tl] = (2.f * s5 - n) * inv;
                }
            }
        }
    }

    // ---- in-block moments over this block's 128 tokens (exact fp32) ----
    __syncthreads();                 // zT/vT complete; sA matrices dead
    float* zpow = (float*)sAbuf;     // alias: 16 rows x ZPH floats = 8448 B
    if (tid < 128) {
        float z = zT[tid];           // thread tid owns token tid
        float pw = 1.f;
#pragma unroll
        for (int m = 0; m < NMOM; ++m) { zpow[m * ZPH + tid] = pw; pw *= z; }
    }
    __syncthreads();
    if (tid < 224) {                 // (m,w) x half: w==6 -> S_m, else H_mw
        int h = (tid >= 112) ? 1 : 0;
        int j = tid - h * 112;
        int m = j / 7, w = j - m * 7;
        const float4* zp = (const float4*)&zpow[m * ZPH + h * 64];
        float a = 0.f;
        if (w == 6) {
#pragma unroll
            for (int k = 0; k < 16; ++k) {
                float4 a4 = zp[k];
                a += a4.x + a4.y + a4.z + a4.w;
            }
        } else {
            const float4* vp = (const float4*)&vT[w * ZPH + h * 64];
#pragma unroll
            for (int k = 0; k < 16; ++k) {
                float4 a4 = zp[k], b4 = vp[k];
                a += a4.x * b4.x + a4.y * b4.y + a4.z * b4.z + a4.w * b4.w;
            }
        }
        sred[tid] = a;
    }
    __syncthreads();
    if (tid < 112) {
        int m = tid / 7, w = tid - m * 7;
        int idx = m * 7 + ((w == 6) ? 0 : (w + 1));   // eval layout: S,H0..H5
        mpart[(size_t)bx * 112 + idx] = sred[tid] + sred[tid + 112];
    }
}

// ---------------------------------------------------------------------------
// Kernel 2: fused combine + per-token evaluation (one block = 256 tokens).
// den = sum_m p_m S_m, out_w = sum_m p_m H_mw, p_m = a^m/m!.
// R19: 16 chunk partials per batch (was 8).
// ---------------------------------------------------------------------------
__global__ __launch_bounds__(256) void qsa_eval(
        const float* __restrict__ zq,
        const float* __restrict__ mpart,
        float* __restrict__ out) {
    __shared__ float sm[112];
    int bk = blockIdx.x;                      // 128 blocks
    int b = bk >> 3;                          // 8 blocks per batch
    int tid = threadIdx.x;
    if (tid < 112) {
        float s = 0.f;
#pragma unroll
        for (int c = 0; c < 16; ++c) s += mpart[(size_t)(b * 16 + c) * 112 + tid];
        sm[tid] = s;
    }
    __syncthreads();

    int t = bk * 256 + tid;
    float a = zq[t];
    float den = 0.f, o0 = 0.f, o1 = 0.f, o2 = 0.f, o3 = 0.f, o4 = 0.f, o5 = 0.f;
    float pw = 1.f;
#pragma unroll
    for (int m = 0; m < NMOM; ++m) {
        const float* mm = sm + m * 7;
        den += pw * mm[0];
        o0 += pw * mm[1]; o1 += pw * mm[2]; o2 += pw * mm[3];
        o3 += pw * mm[4]; o4 += pw * mm[5]; o5 += pw * mm[6];
        pw *= a * (1.0f / (m + 1));           // p_{m+1} = p_m * a/(m+1)
    }
    float inv = 1.0f / den;
    float* o = out + (size_t)t * 6;
    float2* o2p = (float2*)o;                 // t*24B is 8-aligned
    o2p[0] = make_float2(o0 * inv, o1 * inv);
    o2p[1] = make_float2(o2 * inv, o3 * inv);
    o2p[2] = make_float2(o4 * inv, o5 * inv);
}

// ---------------------------------------------------------------------------
extern "C" void kernel_launch(void* const* d_in, const int* in_sizes, int n_in,
                              void* d_out, int out_size, void* d_ws, size_t ws_size,
                              hipStream_t stream) {
    const float* x  = (const float*)d_in[0];
    const float* pq = (const float*)d_in[1];
    const float* pk = (const float*)d_in[2];
    const float* pv = (const float*)d_in[3];
    float* w = (float*)d_ws;
    // ws (floats): zq[32768] | mpart[256*112]
    float* zq    = w;
    float* mpart = zq + NTOK;
    float* out   = (float*)d_out;

    qsa_sim<<<256, 256, 0, stream>>>(x, pq, pk, pv, zq, mpart);
    qsa_eval<<<NTOK / 256, 256, 0, stream>>>(zq, mpart, out);
}

// Round 7
// 84.714 us; speedup vs baseline: 1.0233x; 1.0233x over previous
//
#include <hip/hip_runtime.h>
#include <math.h>

#define NWIRES 6
#define DIM 64
#define NTOK 32768            // B*T = 16*2048
#define NBATCH 16
#define TPB 2048              // tokens per batch
#define NMOM 16               // Taylor order: exp(az), |az|<=sqrt(6); rem ~8e-8
#define SQRT6F 2.4494897427831781f
#define APAD 76               // LDS row stride (ushorts), conflict-benign (R12)
#define ZP 260                // zpow/vT row stride (floats): 16B-aligned rows

typedef short bf16x8 __attribute__((ext_vector_type(8)));
typedef float f32x4  __attribute__((ext_vector_type(4)));

__device__ __forceinline__ unsigned f2bfbits(float f) {   // RNE fp32->bf16 bits
    unsigned u = __float_as_uint(f);
    return (u + 0x7FFF + ((u >> 16) & 1)) >> 16;
}
__device__ __forceinline__ float bfbits2f(unsigned b) {
    return __uint_as_float(b << 16);
}
__device__ __forceinline__ float pswap(float v) { return __shfl_xor(v, 1, 64); }

// ---------------------------------------------------------------------------
// R20 = R17 byte-for-byte (the session's measured best: 85.4us).
// Ledger: R13=85.9 R14=88.1 R15=87.8 R16=88.5 R17=85.4 R18=FAIL R19=86.7.
// Every intra-kernel restructure is sub-noise; dispatch count (2) is at the
// graph-capture floor.  This revert locks in the best verified config and
// double-samples R17 for a noise estimate before declaring the roofline.
//   Grid (128, 2):
//   circ0 block bx: Q circuit for tokens [bx*256, bx*256+256) -> zq
//   circ1 block bx: K AND V circuits for the same tokens (x fragments shared),
//     then the chunk's moment partials computed IN-BLOCK -> mpart directly.
// ---------------------------------------------------------------------------

// A-build device fn: angle tables + R12 half-column evolution -> sAh/sAl.
// Called by ALL threads of the block (contains barriers).
__device__ __forceinline__ void build_A(const float* __restrict__ p,
        unsigned short* sAh, unsigned short* sAl,
        float* sTc, float* sTs, float* sP, int tid) {
    if (tid < 64) {
        int b = tid;
        float d = 0.f;
#pragma unroll
        for (int j = 0; j < 6; ++j)
            d += 0.5f * p[j] * ((b & (32 >> j)) ? -1.f : 1.f);
        float sd, cd;
        sincosf(d, &sd, &cd);
        sTc[b] = cd;
        sTs[b] = sd;
        if (b < 12) {                     // p[6..11]=RY0, p[12..17]=RY1
            float s, cc;
            sincosf(0.5f * p[6 + b], &s, &cc);
            sP[b * 2 + 0] = cc;
            sP[b * 2 + 1] = s;
        }
    }
    __syncthreads();

    {
        int ph = tid >> 7;                // 0: cos rows, 1: sin rows
        int k  = (tid >> 1) & 63;         // column
        int h  = tid & 1;                 // bit5 (value 32) of row index
        const float* sTx = ph ? sTs : sTc;
        float v[32];
#pragma unroll
        for (int i = 0; i < 32; ++i) {
            int g = h * 32 + i;
            v[i] = (__popc(g & k) & 1) ? -sTx[g] : sTx[g];   // diag(T) W e_k
        }
        // Walsh stage M=32 (split): lo'=lo+hi, hi'=lo-hi
#pragma unroll
        for (int i = 0; i < 32; ++i) {
            float pv_ = pswap(v[i]);
            v[i] = h ? (pv_ - v[i]) : (v[i] + pv_);
        }
        // Walsh stages M=16..1 (local)
#pragma unroll
        for (int M = 16; M >= 1; M >>= 1) {
#pragma unroll
            for (int i = 0; i < 32; ++i) {
                if (i & M) continue;
                int j = i | M;
                float a = v[i], b = v[j];
                v[i] = a + b; v[j] = a - b;
            }
        }
        // RY0 then CNOT ring then RY1
#pragma unroll
        for (int layer = 0; layer < 2; ++layer) {
            const float* Pl = sP + layer * 12;
            {
                float c = Pl[0], ss = h ? Pl[1] : -Pl[1];
#pragma unroll
                for (int i = 0; i < 32; ++i) {
                    float pv_ = pswap(v[i]);
                    v[i] = c * v[i] + ss * pv_;
                }
            }
#pragma unroll
            for (int w = 1; w < 6; ++w) {
                int M = 32 >> w;
                float c = Pl[w * 2], s = Pl[w * 2 + 1];
#pragma unroll
                for (int i = 0; i < 32; ++i) {
                    if (i & M) continue;
                    int j = i | M;
                    float a = v[i], b = v[j];
                    v[i] = c * a - s * b;
                    v[j] = s * a + c * b;
                }
            }
            if (layer == 0) {
                // CNOT(0,1): control bit32 (h), target 16
#pragma unroll
                for (int i = 0; i < 16; ++i) {
                    int j = i | 16;
                    float a = v[i], b = v[j];
                    v[i] = h ? b : a;
                    v[j] = h ? a : b;
                }
                // CNOT(1,2)(2,3)(3,4)(4,5): local renames
#pragma unroll
                for (int w = 1; w < 5; ++w) {
                    int MC = 32 >> w, MT = MC >> 1;
#pragma unroll
                    for (int i = 0; i < 32; ++i) {
                        if (!(i & MC) || (i & MT)) continue;
                        int j = i | MT;
                        float t = v[i]; v[i] = v[j]; v[j] = t;
                    }
                }
                // CNOT(5,0): control bit0, target bit32
#pragma unroll
                for (int i = 1; i < 32; i += 2) v[i] = pswap(v[i]);
            }
        }
        // pack bf16 hi/lo into LDS
#pragma unroll
        for (int i = 0; i < 32; ++i) {
            int row = ph * 64 + h * 32 + i;
            unsigned hb = f2bfbits(v[i]);
            unsigned lb = f2bfbits(v[i] - bfbits2f(hb));
            sAh[row * APAD + k] = (unsigned short)hb;
            sAl[row * APAD + k] = (unsigned short)lb;
        }
    }
    __syncthreads();
}

__global__ __attribute__((amdgpu_waves_per_eu(1, 4)))
__launch_bounds__(256) void qsa_sim(
        const float* __restrict__ x,
        const float* __restrict__ pq,
        const float* __restrict__ pk,
        const float* __restrict__ pv,
        float* __restrict__ zq,
        float* __restrict__ mpart) {
    // slot0: Q or K matrices; slot1: V matrices (circ1 only).
    __shared__ __align__(16) unsigned short sAbuf[4 * 128 * APAD];  // 77824 B
    __shared__ float sTc[64], sTs[64], sP[24];
    __shared__ float zT[256];                       // K-circuit z per token
    __shared__ __align__(16) float vT[6 * ZP];      // V outputs, transposed
    __shared__ float sred[224];
    int tid = threadIdx.x;
    int tbase = blockIdx.x * 256;
    int circ = blockIdx.y;                          // 0: Q;  1: K+V+moments

    // ---- issue pair-0 X loads first (cg 0 and 1; overlap with build) ----
    int lane = tid & 63, wv = tid >> 6;
    int q4 = lane >> 4, c16 = lane & 15;
    float4 rw[8];
#pragma unroll
    for (int cg = 0; cg < 2; ++cg) {
        const float* xr = x + ((size_t)(tbase + wv * 64 + cg * 16 + c16)) * 64;
#pragma unroll
        for (int ks = 0; ks < 2; ++ks) {
            rw[cg * 4 + ks * 2 + 0] = *(const float4*)(xr + ks * 32 + q4 * 8);
            rw[cg * 4 + ks * 2 + 1] = *(const float4*)(xr + ks * 32 + q4 * 8 + 4);
        }
    }

    // ---- build A matrices ----
    int ncirc;
    if (circ == 0) {
        build_A(pq, sAbuf, sAbuf + 128 * APAD, sTc, sTs, sP, tid);
        ncirc = 1;
    } else {
        build_A(pk, sAbuf, sAbuf + 128 * APAD, sTc, sTs, sP, tid);
        build_A(pv, sAbuf + 2 * 128 * APAD, sAbuf + 3 * 128 * APAD,
                sTc, sTs, sP, tid);
        ncirc = 2;
    }

    // ---- MFMA: 2 pairs x 2 chunk-groups; x fragments shared across circs ----
    bf16x8 xh[2][2], xl[2][2];
#pragma unroll 1
    for (int pr = 0; pr < 2; ++pr) {
        // convert this pair's raws -> fragments (once per pair, shared K/V)
#pragma unroll
        for (int cg = 0; cg < 2; ++cg) {
#pragma unroll
            for (int ks = 0; ks < 2; ++ks) {
                float4 f0 = rw[cg * 4 + ks * 2], f1 = rw[cg * 4 + ks * 2 + 1];
                float ff[8] = {f0.x, f0.y, f0.z, f0.w, f1.x, f1.y, f1.z, f1.w};
#pragma unroll
                for (int e = 0; e < 8; ++e) {
                    unsigned hb = f2bfbits(ff[e]);
                    unsigned lb = f2bfbits(ff[e] - bfbits2f(hb));
                    xh[cg][ks][e] = (short)hb;
                    xl[cg][ks][e] = (short)lb;
                }
            }
        }
        // prefetch next pair's raws (overlaps MFMAs below)
        if (pr == 0) {
#pragma unroll
            for (int cg = 0; cg < 2; ++cg) {
                const float* xr = x + ((size_t)(tbase + wv * 64 + (2 + cg) * 16 + c16)) * 64;
#pragma unroll
                for (int ks = 0; ks < 2; ++ks) {
                    rw[cg * 4 + ks * 2 + 0] = *(const float4*)(xr + ks * 32 + q4 * 8);
                    rw[cg * 4 + ks * 2 + 1] = *(const float4*)(xr + ks * 32 + q4 * 8 + 4);
                }
            }
        }

#pragma unroll 1
        for (int cc = 0; cc < ncirc; ++cc) {
            const unsigned short* Ah = sAbuf + cc * (2 * 128 * APAD);
            const unsigned short* Al = Ah + 128 * APAD;

            f32x4 acc[2][8];
#pragma unroll
            for (int cg = 0; cg < 2; ++cg)
#pragma unroll
                for (int mt = 0; mt < 8; ++mt) acc[cg][mt] = (f32x4){0.f, 0.f, 0.f, 0.f};

#pragma unroll
            for (int mt = 0; mt < 8; ++mt) {
                int r = mt * 16 + c16;               // A-op row m
#pragma unroll
                for (int ks = 0; ks < 2; ++ks) {
                    const uint2* ph_ = (const uint2*)(&Ah[r * APAD + ks * 32 + q4 * 8]);
                    const uint2* pl_ = (const uint2*)(&Al[r * APAD + ks * 32 + q4 * 8]);
                    union { uint2 u[2]; bf16x8 v; } ua, ub;
                    ua.u[0] = ph_[0]; ua.u[1] = ph_[1];
                    ub.u[0] = pl_[0]; ub.u[1] = pl_[1];
                    bf16x8 ah = ua.v, al = ub.v;
#pragma unroll
                    for (int cg = 0; cg < 2; ++cg) {
                        acc[cg][mt] = __builtin_amdgcn_mfma_f32_16x16x32_bf16(ah, xh[cg][ks], acc[cg][mt], 0, 0, 0);
                        acc[cg][mt] = __builtin_amdgcn_mfma_f32_16x16x32_bf16(ah, xl[cg][ks], acc[cg][mt], 0, 0, 0);
                        acc[cg][mt] = __builtin_amdgcn_mfma_f32_16x16x32_bf16(al, xh[cg][ks], acc[cg][mt], 0, 0, 0);
                    }
                }
            }

            // epilogue per chunk-group (R12-verified math)
#pragma unroll
            for (int cg = 0; cg < 2; ++cg) {
                float n = 0.f, s0 = 0.f, s1 = 0.f, s2 = 0.f, s3 = 0.f, s4 = 0.f, s5 = 0.f;
                float f2 = (q4 < 2) ? 1.f : 0.f;         // r bit3 == 0
                float f3 = (q4 & 1) ? 0.f : 1.f;         // r bit2 == 0
#pragma unroll
                for (int mt = 0; mt < 4; ++mt) {
#pragma unroll
                    for (int rg = 0; rg < 4; ++rg) {
                        float dc = acc[cg][mt][rg];      // row r = mt*16 + q4*4 + rg
                        float ds = acc[cg][mt + 4][rg];  // row r + 64
                        float pp = dc * dc + ds * ds;
                        n += pp;
                        if (!(mt & 2)) s0 += pp;         // bit5
                        if (!(mt & 1)) s1 += pp;         // bit4
                        s2 += f2 * pp;                   // bit3
                        s3 += f3 * pp;                   // bit2
                        if (!(rg & 2)) s4 += pp;         // bit1
                        if (!(rg & 1)) s5 += pp;         // bit0
                    }
                }
#pragma unroll
                for (int d = 16; d <= 32; d <<= 1) {
                    n  += __shfl_xor(n,  d, 64);
                    s0 += __shfl_xor(s0, d, 64);
                    s1 += __shfl_xor(s1, d, 64);
                    s2 += __shfl_xor(s2, d, 64);
                    s3 += __shfl_xor(s3, d, 64);
                    s4 += __shfl_xor(s4, d, 64);
                    s5 += __shfl_xor(s5, d, 64);
                }
                if (q4 == 0) {
                    int tl = wv * 64 + (pr * 2 + cg) * 16 + c16;
                    float inv = 1.0f / n;
                    if (circ == 0) {
                        zq[tbase + tl] = SQRT6F * (2.f * s0 - n) * inv;  // a_t
                    } else if (cc == 0) {
                        zT[tl] = (2.f * s0 - n) * inv;                   // K z
                    } else {
                        vT[0 * ZP + tl] = (2.f * s0 - n) * inv;
                        vT[1 * ZP + tl] = (2.f * s1 - n) * inv;
                        vT[2 * ZP + tl] = (2.f * s2 - n) * inv;
                        vT[3 * ZP + tl] = (2.f * s3 - n) * inv;
                        vT[4 * ZP + tl] = (2.f * s4 - n) * inv;
                        vT[5 * ZP + tl] = (2.f * s5 - n) * inv;
                    }
                }
            }
        }
    }

    // ---- in-block moments (circ1 only): exact fp32, transposed reduction ----
    if (circ == 1) {
        __syncthreads();                 // zT/vT complete; sA matrices dead
        float* zpow = (float*)sAbuf;     // alias: 16 rows x ZP floats = 16.6 KB
        {
            float z = zT[tid];           // thread tid owns token tid
            float pw = 1.f;
#pragma unroll
            for (int m = 0; m < NMOM; ++m) { zpow[m * ZP + tid] = pw; pw *= z; }
        }
        __syncthreads();
        if (tid < 224) {                 // (m,w) x half: w==6 -> S_m, else H_mw
            int h = (tid >= 112) ? 1 : 0;
            int j = tid - h * 112;
            int m = j / 7, w = j - m * 7;
            const float4* zp = (const float4*)&zpow[m * ZP + h * 128];
            float a = 0.f;
            if (w == 6) {
#pragma unroll
                for (int k = 0; k < 32; ++k) {
                    float4 a4 = zp[k];
                    a += a4.x + a4.y + a4.z + a4.w;
                }
            } else {
                const float4* vp = (const float4*)&vT[w * ZP + h * 128];
#pragma unroll
                for (int k = 0; k < 32; ++k) {
                    float4 a4 = zp[k], b4 = vp[k];
                    a += a4.x * b4.x + a4.y * b4.y + a4.z * b4.z + a4.w * b4.w;
                }
            }
            sred[tid] = a;
        }
        __syncthreads();
        if (tid < 112) {
            int m = tid / 7, w = tid - m * 7;
            int idx = m * 7 + ((w == 6) ? 0 : (w + 1));   // eval layout: S,H0..H5
            mpart[(size_t)blockIdx.x * 112 + idx] = sred[tid] + sred[tid + 112];
        }
    }
}

// ---------------------------------------------------------------------------
// Kernel 2: fused combine + per-token evaluation (one block = 256 tokens).
// den = sum_m p_m S_m, out_w = sum_m p_m H_mw, p_m = a^m/m!.  Unchanged.
// ---------------------------------------------------------------------------
__global__ __launch_bounds__(256) void qsa_eval(
        const float* __restrict__ zq,
        const float* __restrict__ mpart,
        float* __restrict__ out) {
    __shared__ float sm[112];
    int bk = blockIdx.x;                      // 128 blocks
    int b = bk >> 3;                          // 8 blocks per batch
    int tid = threadIdx.x;
    if (tid < 112) {
        float s = 0.f;
#pragma unroll
        for (int c = 0; c < 8; ++c) s += mpart[(size_t)(b * 8 + c) * 112 + tid];
        sm[tid] = s;
    }
    __syncthreads();

    int t = bk * 256 + tid;
    float a = zq[t];
    float den = 0.f, o0 = 0.f, o1 = 0.f, o2 = 0.f, o3 = 0.f, o4 = 0.f, o5 = 0.f;
    float pw = 1.f;
#pragma unroll
    for (int m = 0; m < NMOM; ++m) {
        const float* mm = sm + m * 7;
        den += pw * mm[0];
        o0 += pw * mm[1]; o1 += pw * mm[2]; o2 += pw * mm[3];
        o3 += pw * mm[4]; o4 += pw * mm[5]; o5 += pw * mm[6];
        pw *= a * (1.0f / (m + 1));           // p_{m+1} = p_m * a/(m+1)
    }
    float inv = 1.0f / den;
    float* o = out + (size_t)t * 6;
    float2* o2p = (float2*)o;                 // t*24B is 8-aligned
    o2p[0] = make_float2(o0 * inv, o1 * inv);
    o2p[1] = make_float2(o2 * inv, o3 * inv);
    o2p[2] = make_float2(o4 * inv, o5 * inv);
}

// ---------------------------------------------------------------------------
extern "C" void kernel_launch(void* const* d_in, const int* in_sizes, int n_in,
                              void* d_out, int out_size, void* d_ws, size_t ws_size,
                              hipStream_t stream) {
    const float* x  = (const float*)d_in[0];
    const float* pq = (const float*)d_in[1];
    const float* pk = (const float*)d_in[2];
    const float* pv = (const float*)d_in[3];
    float* w = (float*)d_ws;
    // ws (floats): zq[32768] | mpart[14336]
    float* zq    = w;
    float* mpart = zq + NTOK;
    float* out   = (float*)d_out;

    qsa_sim<<<dim3(NTOK / 256, 2), 256, 0, stream>>>(x, pq, pk, pv, zq, mpart);
    qsa_eval<<<NTOK / 256, 256, 0, stream>>>(zq, mpart, out);
}

// Round 8
// 83.353 us; speedup vs baseline: 1.0400x; 1.0163x over previous
//
#include <hip/hip_runtime.h>
#include <math.h>

#define NWIRES 6
#define DIM 64
#define NTOK 32768            // B*T = 16*2048
#define NBATCH 16
#define TPB 2048              // tokens per batch
#define NMOM 16               // Taylor order: exp(az), |az|<=sqrt(6); rem ~8e-8
#define SQRT6F 2.4494897427831781f
#define FRAG 512              // ushorts per A-fragment (64 lanes x 8)
#define CSTRIDE 16384         // ushorts per circuit (2 planes x 16 frags x 512)

typedef short bf16x8 __attribute__((ext_vector_type(8)));
typedef float f32x4  __attribute__((ext_vector_type(4)));

__device__ __forceinline__ unsigned f2bfbits(float f) {   // RNE fp32->bf16 bits
    unsigned u = __float_as_uint(f);
    return (u + 0x7FFF + ((u >> 16) & 1)) >> 16;
}
__device__ __forceinline__ float bfbits2f(unsigned b) {
    return __uint_as_float(b << 16);
}

// ---------------------------------------------------------------------------
// R21: occupancy attack.  R20's profile finally showed qsa_sim: 57-63us
// profiled, Occupancy 8.7% (87KB LDS -> 1 block/CU -> 1 wave/SIMD),
// MfmaUtil 2.7%, VALUBusy 10%, HBM 1% -> pure latency-bound; explains why
// all R13-R19 restructures (all >=39KB LDS, <=1.5 blocks/CU) were flat.
// Fix: A matrices leave LDS entirely.
//   k0 qsa_build (3 blocks): build A and store to global in MFMA FRAGMENT
//      layout: frag(cc,plane,mt,ks) = 1KB, lane l holds bytes [l*16,l*16+16)
//      = A[row=mt*16+(l&15)][col=ks*32+(l>>4)*8+e], e=0..7.  Sim loads each
//      A-operand as ONE coalesced dwordx4 from L2 (gA = 96KB, chip-resident).
//   k1 qsa_sim: grid (512,2), 64 tokens/block, LDS 6.2KB -> 4 blocks/CU,
//      16 waves/CU (VGPR ~100 < 128 cap).  Wave owns 16 tokens (1 cg).
//      Per-token MFMA math and order byte-identical to R12-R20.
//   k2 qsa_eval: unchanged (32 partials/batch now).
// ---------------------------------------------------------------------------
__global__ __launch_bounds__(128) void qsa_build(
        const float* __restrict__ pq,
        const float* __restrict__ pk,
        const float* __restrict__ pv,
        unsigned short* __restrict__ gA) {
    __shared__ float sTc[64], sTs[64], sP[24];
    int circ = blockIdx.x;
    const float* p = (circ == 0) ? pq : (circ == 1 ? pk : pv);
    int tid = threadIdx.x;

    if (tid < 64) {                       // angle tables (R14-verified)
        int b = tid;
        float d = 0.f;
#pragma unroll
        for (int j = 0; j < 6; ++j)
            d += 0.5f * p[j] * ((b & (32 >> j)) ? -1.f : 1.f);
        float sd, cd;
        sincosf(d, &sd, &cd);
        sTc[b] = cd;
        sTs[b] = sd;
        if (b < 12) {                     // p[6..11]=RY0, p[12..17]=RY1
            float s, cc;
            sincosf(0.5f * p[6 + b], &s, &cc);
            sP[b * 2 + 0] = cc;
            sP[b * 2 + 1] = s;
        }
    }
    __syncthreads();

    int ph = tid >> 6;                    // 0: cos rows, 1: sin rows
    int k  = tid & 63;                    // column
    const float* sTx = ph ? sTs : sTc;
    float v[64];
#pragma unroll
    for (int g = 0; g < 64; ++g)          // diag(T) W e_k
        v[g] = (__popc(g & k) & 1) ? -sTx[g] : sTx[g];

    // Walsh stages M=32..1 (all thread-local; R14-verified)
#pragma unroll
    for (int M = 32; M >= 1; M >>= 1) {
#pragma unroll
        for (int i = 0; i < 64; ++i) {
            if (i & M) continue;
            int j = i | M;
            float a = v[i], b = v[j];
            v[i] = a + b; v[j] = a - b;
        }
    }

    // RY0, CNOT ring, RY1 (R14-verified)
#pragma unroll
    for (int layer = 0; layer < 2; ++layer) {
        const float* Pl = sP + layer * 12;
#pragma unroll
        for (int w = 0; w < 6; ++w) {     // wire w acts on bit (32>>w)
            int M = 32 >> w;
            float c = Pl[w * 2], s = Pl[w * 2 + 1];
#pragma unroll
            for (int i = 0; i < 64; ++i) {
                if (i & M) continue;
                int j = i | M;
                float a = v[i], b = v[j];
                v[i] = c * a - s * b;
                v[j] = s * a + c * b;
            }
        }
        if (layer == 0) {
            // CNOT(0,1): control bit32, target bit16
#pragma unroll
            for (int i = 32; i < 64; ++i) {
                if (i & 16) continue;
                int j = i | 16;
                float t = v[i]; v[i] = v[j]; v[j] = t;
            }
            // CNOT(1,2)(2,3)(3,4)(4,5)
#pragma unroll
            for (int w = 1; w < 5; ++w) {
                int MC = 32 >> w, MT = MC >> 1;
#pragma unroll
                for (int i = 0; i < 64; ++i) {
                    if (!(i & MC) || (i & MT)) continue;
                    int j = i | MT;
                    float t = v[i]; v[i] = v[j]; v[j] = t;
                }
            }
            // CNOT(5,0): control bit0, target bit32
#pragma unroll
            for (int i = 1; i < 32; i += 2) {
                int j = i | 32;
                float t = v[i]; v[i] = v[j]; v[j] = t;
            }
        }
    }

    // store in MFMA fragment layout (hi plane at 0, lo plane at +8192)
    unsigned short* g0 = gA + (size_t)circ * CSTRIDE;
    int ks = k >> 5, q4 = (k >> 3) & 3, e = k & 7;
#pragma unroll
    for (int i = 0; i < 64; ++i) {
        int r = ph * 64 + i;              // A row 0..127
        int mt = r >> 4, c16 = r & 15;
        int l = q4 * 16 + c16;            // MFMA lane
        int off = ((mt * 2 + ks) << 9) + l * 8 + e;
        unsigned hb = f2bfbits(v[i]);
        unsigned lb = f2bfbits(v[i] - bfbits2f(hb));
        g0[off] = (unsigned short)hb;
        g0[8192 + off] = (unsigned short)lb;
    }
}

// ---------------------------------------------------------------------------
// Kernel 1: MFMA sim, zero-LDS A.  Grid (512, 2): 64-token tile, role.
// ---------------------------------------------------------------------------
__global__ __attribute__((amdgpu_waves_per_eu(1, 4)))
__launch_bounds__(256) void qsa_sim(
        const float* __restrict__ x,
        const unsigned short* __restrict__ gA,
        float* __restrict__ zq,
        float* __restrict__ mpart) {
    __shared__ float zT[64];                       // K-circuit z per token
    __shared__ __align__(16) float vT[6 * 68];     // V outputs, transposed
    __shared__ __align__(16) float zpow[16 * 68];  // z powers
    int tid = threadIdx.x;
    int bx = blockIdx.x;                           // 0..511
    int circ = blockIdx.y;                         // 0: Q;  1: K+V+moments
    int tbase = bx * 64;

    int lane = tid & 63, wv = tid >> 6;
    int q4 = lane >> 4, c16 = lane & 15;

    // ---- load this wave's 16 tokens (4 float4/lane) ----
    const float* xr = x + ((size_t)(tbase + wv * 16 + c16)) * 64;
    float4 rw[4];
#pragma unroll
    for (int ks = 0; ks < 2; ++ks) {
        rw[ks * 2 + 0] = *(const float4*)(xr + ks * 32 + q4 * 8);
        rw[ks * 2 + 1] = *(const float4*)(xr + ks * 32 + q4 * 8 + 4);
    }

    // ---- convert x -> bf16 hi/lo fragments ----
    bf16x8 xh[2], xl[2];
#pragma unroll
    for (int ks = 0; ks < 2; ++ks) {
        float4 f0 = rw[ks * 2], f1 = rw[ks * 2 + 1];
        float ff[8] = {f0.x, f0.y, f0.z, f0.w, f1.x, f1.y, f1.z, f1.w};
#pragma unroll
        for (int e = 0; e < 8; ++e) {
            unsigned hb = f2bfbits(ff[e]);
            unsigned lb = f2bfbits(ff[e] - bfbits2f(hb));
            xh[ks][e] = (short)hb;
            xl[ks][e] = (short)lb;
        }
    }

    // ---- circuits: Q blocks do cc=0; KV blocks do cc=1 (K), cc=2 (V) ----
    int cc0 = circ ? 1 : 0;
    int nc  = circ ? 2 : 1;
#pragma unroll 1
    for (int ci = 0; ci < nc; ++ci) {
        int cc = cc0 + ci;
        const unsigned short* Af = gA + (size_t)cc * CSTRIDE;

        f32x4 acc[8];
#pragma unroll
        for (int mt = 0; mt < 8; ++mt) acc[mt] = (f32x4){0.f, 0.f, 0.f, 0.f};

#pragma unroll
        for (int mt = 0; mt < 8; ++mt) {
#pragma unroll
            for (int ks = 0; ks < 2; ++ks) {
                int off = ((mt * 2 + ks) << 9) + lane * 8;
                union { uint4 u; bf16x8 v; } ua, ub;
                ua.u = *(const uint4*)(Af + off);          // hi plane
                ub.u = *(const uint4*)(Af + 8192 + off);   // lo plane
                acc[mt] = __builtin_amdgcn_mfma_f32_16x16x32_bf16(ua.v, xh[ks], acc[mt], 0, 0, 0);
                acc[mt] = __builtin_amdgcn_mfma_f32_16x16x32_bf16(ua.v, xl[ks], acc[mt], 0, 0, 0);
                acc[mt] = __builtin_amdgcn_mfma_f32_16x16x32_bf16(ub.v, xh[ks], acc[mt], 0, 0, 0);
            }
        }

        // epilogue (R12-verified math)
        float n = 0.f, s0 = 0.f, s1 = 0.f, s2 = 0.f, s3 = 0.f, s4 = 0.f, s5 = 0.f;
        float f2 = (q4 < 2) ? 1.f : 0.f;         // r bit3 == 0
        float f3 = (q4 & 1) ? 0.f : 1.f;         // r bit2 == 0
#pragma unroll
        for (int mt = 0; mt < 4; ++mt) {
#pragma unroll
            for (int rg = 0; rg < 4; ++rg) {
                float dc = acc[mt][rg];          // row r = mt*16 + q4*4 + rg
                float ds = acc[mt + 4][rg];      // row r + 64
                float pp = dc * dc + ds * ds;
                n += pp;
                if (!(mt & 2)) s0 += pp;         // bit5
                if (!(mt & 1)) s1 += pp;         // bit4
                s2 += f2 * pp;                   // bit3
                s3 += f3 * pp;                   // bit2
                if (!(rg & 2)) s4 += pp;         // bit1
                if (!(rg & 1)) s5 += pp;         // bit0
            }
        }
#pragma unroll
        for (int d = 16; d <= 32; d <<= 1) {
            n  += __shfl_xor(n,  d, 64);
            s0 += __shfl_xor(s0, d, 64);
            s1 += __shfl_xor(s1, d, 64);
            s2 += __shfl_xor(s2, d, 64);
            s3 += __shfl_xor(s3, d, 64);
            s4 += __shfl_xor(s4, d, 64);
            s5 += __shfl_xor(s5, d, 64);
        }
        if (q4 == 0) {
            int tl = wv * 16 + c16;              // 0..63
            float inv = 1.0f / n;
            if (circ == 0) {
                zq[tbase + tl] = SQRT6F * (2.f * s0 - n) * inv;  // a_t
            } else if (cc == 1) {
                zT[tl] = (2.f * s0 - n) * inv;                   // K z
            } else {
                vT[0 * 68 + tl] = (2.f * s0 - n) * inv;
                vT[1 * 68 + tl] = (2.f * s1 - n) * inv;
                vT[2 * 68 + tl] = (2.f * s2 - n) * inv;
                vT[3 * 68 + tl] = (2.f * s3 - n) * inv;
                vT[4 * 68 + tl] = (2.f * s4 - n) * inv;
                vT[5 * 68 + tl] = (2.f * s5 - n) * inv;
            }
        }
    }

    // ---- in-block moments over 64 tokens (KV blocks; exact fp32) ----
    if (circ == 1) {
        __syncthreads();                 // zT/vT complete
        if (tid < 64) {
            float z = zT[tid];           // thread tid owns token tid
            float pw = 1.f;
#pragma unroll
            for (int m = 0; m < NMOM; ++m) { zpow[m * 68 + tid] = pw; pw *= z; }
        }
        __syncthreads();
        if (tid < 112) {                 // (m,w): w==6 -> S_m, else H_mw
            int m = tid / 7, w = tid - m * 7;
            const float4* zp = (const float4*)&zpow[m * 68];
            float a = 0.f;
            if (w == 6) {
#pragma unroll
                for (int k = 0; k < 16; ++k) {
                    float4 a4 = zp[k];
                    a += a4.x + a4.y + a4.z + a4.w;
                }
            } else {
                const float4* vp = (const float4*)&vT[w * 68];
#pragma unroll
                for (int k = 0; k < 16; ++k) {
                    float4 a4 = zp[k], b4 = vp[k];
                    a += a4.x * b4.x + a4.y * b4.y + a4.z * b4.z + a4.w * b4.w;
                }
            }
            int idx = m * 7 + ((w == 6) ? 0 : (w + 1));   // eval layout: S,H0..H5
            mpart[(size_t)bx * 112 + idx] = a;
        }
    }
}

// ---------------------------------------------------------------------------
// Kernel 2: fused combine + per-token evaluation (one block = 256 tokens).
// den = sum_m p_m S_m, out_w = sum_m p_m H_mw, p_m = a^m/m!.
// R21: 32 chunk partials per batch (64-token chunks).
// ---------------------------------------------------------------------------
__global__ __launch_bounds__(256) void qsa_eval(
        const float* __restrict__ zq,
        const float* __restrict__ mpart,
        float* __restrict__ out) {
    __shared__ float sm[112];
    int bk = blockIdx.x;                      // 128 blocks
    int b = bk >> 3;                          // 8 blocks per batch
    int tid = threadIdx.x;
    if (tid < 112) {
        float s = 0.f;
#pragma unroll
        for (int c = 0; c < 32; ++c) s += mpart[(size_t)(b * 32 + c) * 112 + tid];
        sm[tid] = s;
    }
    __syncthreads();

    int t = bk * 256 + tid;
    float a = zq[t];
    float den = 0.f, o0 = 0.f, o1 = 0.f, o2 = 0.f, o3 = 0.f, o4 = 0.f, o5 = 0.f;
    float pw = 1.f;
#pragma unroll
    for (int m = 0; m < NMOM; ++m) {
        const float* mm = sm + m * 7;
        den += pw * mm[0];
        o0 += pw * mm[1]; o1 += pw * mm[2]; o2 += pw * mm[3];
        o3 += pw * mm[4]; o4 += pw * mm[5]; o5 += pw * mm[6];
        pw *= a * (1.0f / (m + 1));           // p_{m+1} = p_m * a/(m+1)
    }
    float inv = 1.0f / den;
    float* o = out + (size_t)t * 6;
    float2* o2p = (float2*)o;                 // t*24B is 8-aligned
    o2p[0] = make_float2(o0 * inv, o1 * inv);
    o2p[1] = make_float2(o2 * inv, o3 * inv);
    o2p[2] = make_float2(o4 * inv, o5 * inv);
}

// ---------------------------------------------------------------------------
extern "C" void kernel_launch(void* const* d_in, const int* in_sizes, int n_in,
                              void* d_out, int out_size, void* d_ws, size_t ws_size,
                              hipStream_t stream) {
    const float* x  = (const float*)d_in[0];
    const float* pq = (const float*)d_in[1];
    const float* pk = (const float*)d_in[2];
    const float* pv = (const float*)d_in[3];
    float* w = (float*)d_ws;
    // ws (floats): zq[32768] | mpart[512*112] | gA (3*16384 ushorts)
    float* zq    = w;
    float* mpart = zq + NTOK;
    unsigned short* gA = (unsigned short*)(mpart + 512 * 112);
    float* out   = (float*)d_out;

    qsa_build<<<3, 128, 0, stream>>>(pq, pk, pv, gA);
    qsa_sim<<<dim3(512, 2), 256, 0, stream>>>(x, gA, zq, mpart);
    qsa_eval<<<NTOK / 256, 256, 0, stream>>>(zq, mpart, out);
}